// Round 7
// baseline (78.593 us; speedup 1.0000x reference)
//
#include <hip/hip_runtime.h>
#include <hip/hip_bf16.h>

#define BATCH 32
#define NNODE 2048
#define NEDGE 8192
#define DIM   512
#define NREL  8
#define VG    50000
#define VS    25000
#define ZI    4608           // 512 (root) + 8*512 (basis)
#define NCH   36             // 4608 / 128 i-chunks
#define TGLOB 3125           // 50000/16 global-head tiles
#define TTOT  4688           // + ceil(25000/16) sense tiles
#define NBLK7 586            // 586 blocks x 8 waves = 4688 waves (1 tile/wave)
#define PG    25             // lse chunks for global head (2048 each)
#define PS    13             // lse chunks for sense head

typedef __attribute__((ext_vector_type(4))) float f32x4;
typedef __attribute__((ext_vector_type(8))) short s16x8;

// ---------------------------------------------------------------------------
// K1: per-batch edge scan (dst==0 only), builds z[g][0..4607]
// ---------------------------------------------------------------------------
__global__ __launch_bounds__(512) void k_conv(const float* __restrict__ x,
                                              const int* __restrict__ ei,
                                              const int* __restrict__ et,
                                              const float* __restrict__ comp,
                                              float* __restrict__ z) {
    int g = blockIdx.x;
    int t = threadIdx.x;
    int wv = t >> 6, lane = t & 63;
    __shared__ int elds[8 * 128];
    __shared__ int wcnt[8];
    const int* srcp = ei + (size_t)(g * 2 + 0) * NEDGE;
    const int* dstp = ei + (size_t)(g * 2 + 1) * NEDGE;

    int run = 0;
    for (int it = 0; it < 16; it++) {
        int e = wv * 1024 + it * 64 + lane;
        bool m = (dstp[e] == 0);
        unsigned long long mask = __ballot(m);
        int rank = __popcll(mask & ((1ull << lane) - 1ull));
        if (m && (run + rank) < 128) elds[wv * 128 + run + rank] = e;
        run += (int)__popcll(mask);
    }
    if (lane == 0) wcnt[wv] = (run > 128) ? 128 : run;
    __syncthreads();

    int d = t;
    float s0=0,s1=0,s2=0,s3=0,s4=0,s5=0,s6=0,s7=0;
    int   c0=0,c1=0,c2=0,c3=0,c4=0,c5=0,c6=0,c7=0;
    for (int w = 0; w < 8; w++) {
        int cw = wcnt[w];
        for (int i = 0; i < cw; i++) {
            int e = elds[w * 128 + i];
            int r = et[(size_t)g * NEDGE + e];
            int sn = srcp[e];
            float val = x[((size_t)g * NNODE + sn) * DIM + d];
            if (r == 0) { s0 += val; c0++; }
            if (r == 1) { s1 += val; c1++; }
            if (r == 2) { s2 += val; c2++; }
            if (r == 3) { s3 += val; c3++; }
            if (r == 4) { s4 += val; c4++; }
            if (r == 5) { s5 += val; c5++; }
            if (r == 6) { s6 += val; c6++; }
            if (r == 7) { s7 += val; c7++; }
        }
    }
    float sv[8] = {s0,s1,s2,s3,s4,s5,s6,s7};
    float inv[8];
    int   cv[8] = {c0,c1,c2,c3,c4,c5,c6,c7};
    #pragma unroll
    for (int r = 0; r < 8; r++) inv[r] = 1.0f / fmaxf((float)cv[r], 1.0f);

    z[(size_t)g * ZI + d] = x[((size_t)g * NNODE + 0) * DIM + d];
    #pragma unroll
    for (int b = 0; b < 8; b++) {
        float y = 0.f;
        #pragma unroll
        for (int r = 0; r < 8; r++) y += comp[r * 8 + b] * inv[r] * sv[r];
        z[(size_t)g * ZI + 512 + b * 512 + d] = y;
    }
}

// ---------------------------------------------------------------------------
// K2a: partial GEMM  part2[c][g][d] = sum_{i in chunk c} z[g][i] * M[i][d]
// ---------------------------------------------------------------------------
__global__ __launch_bounds__(512) void k_gemm_part(const float* __restrict__ z,
                                                   const float* __restrict__ root,
                                                   const float* __restrict__ basis,
                                                   float* __restrict__ part2) {
    int bx = blockIdx.x;
    int dt = bx & 3;
    int cc = bx >> 2;
    int t = threadIdx.x;
    int dl = t & 127, gq = t >> 7;
    __shared__ float ztT[128][33];
    #pragma unroll
    for (int rep = 0; rep < 8; rep++) {
        int flat = rep * 512 + t;
        int g = flat >> 7, i = flat & 127;
        ztT[i][g] = z[(size_t)g * ZI + cc * 128 + i];
    }
    __syncthreads();
    const float* M = (cc < 4) ? (root + (size_t)(cc * 128) * 512)
                              : (basis + (size_t)((cc - 4) * 128) * 512);
    float acc[8] = {0,0,0,0,0,0,0,0};
    for (int i = 0; i < 128; i++) {
        float m = M[(size_t)i * 512 + dt * 128 + dl];
        #pragma unroll
        for (int j = 0; j < 8; j++) acc[j] += ztT[i][gq * 8 + j] * m;
    }
    #pragma unroll
    for (int j = 0; j < 8; j++) {
        int g = gq * 8 + j;
        part2[((size_t)cc * 32 + g) * 512 + dt * 128 + dl] = acc[j];
    }
}

// ---------------------------------------------------------------------------
// K2b: h0 reduce + relu + pack bf16 pairs.  h0t[g*256 + p] = bf16(2p)|bf16(2p+1)<<16
// ---------------------------------------------------------------------------
__device__ __forceinline__ unsigned bf16rne(float f) {
    unsigned u = __float_as_uint(f);
    return (u + 0x7FFFu + ((u >> 16) & 1u)) >> 16;
}

__global__ __launch_bounds__(256) void k_h0(const float* __restrict__ part2,
                                            const float* __restrict__ bias_conv,
                                            unsigned* __restrict__ h0t) {
    int g = blockIdx.x;
    int p = threadIdx.x;          // pair index kp = 0..255
    int d0 = 2 * p;
    float v0 = bias_conv[d0], v1 = bias_conv[d0 + 1];
    for (int cc = 0; cc < NCH; cc++) {
        const float* pp = part2 + ((size_t)cc * 32 + g) * 512 + d0;
        v0 += pp[0];
        v1 += pp[1];
    }
    v0 = fmaxf(v0, 0.f);
    v1 = fmaxf(v1, 0.f);
    h0t[g * 256 + p] = bf16rne(v0) | (bf16rne(v1) << 16);
}

// ---------------------------------------------------------------------------
// K3 v7: wave-private continuous-stream MFMA GEMV.
// 586 blocks x 8 waves = 4688 waves; each wave owns ONE 16-row x K=512 tile
// (32KB of W) and streams it through a rolling 4-deep register pipeline:
// consume wb[kc&3], immediately issue kc+4. Full unroll -> static buffer
// indices; the compiler emits counted vmcnt waits (no hand waitcnt, no
// barriers after h0 staging, no gload_lds, no WG churn stalls: streams are
// continuous for the wave's whole life).
// h0 (A-fragments) in 32KB XOR-swizzled LDS, loaded once per block.
// LDS 32KB, VGPR<=128 (launch_bounds 512,4) -> 2 blocks/CU = 16 waves/CU,
// ~128KB of W in flight per CU sustained.
// ---------------------------------------------------------------------------
__device__ __forceinline__ short f2bf(float f) {
    __hip_bfloat16 h = __float2bfloat16(f);
    return *reinterpret_cast<short*>(&h);
}

__global__ __launch_bounds__(512, 4) void k_logits7(const unsigned* __restrict__ h0t,
                                                    const float* __restrict__ wg,
                                                    const float* __restrict__ bg,
                                                    const float* __restrict__ wsn,
                                                    const float* __restrict__ bsv,
                                                    float* __restrict__ out) {
    __shared__ __align__(16) unsigned char hlds[32768];   // h0 [32 g][1KB], 16B-XOR

    int t = threadIdx.x;          // 0..511
    int wv = t >> 6, l = t & 63;

    // ---- h0 -> LDS (16B-granule XOR by batch row); once per block ----
    #pragma unroll
    for (int rep = 0; rep < 4; rep++) {
        int idx = rep * 512 + t;               // uint4 index, 2048 total
        int g = idx >> 6, q = idx & 63;
        uint4 val = *(const uint4*)&h0t[idx * 4];
        *(uint4*)&hlds[g * 1024 + ((q ^ (g & 7)) << 4)] = val;
    }
    __syncthreads();

    // ---- wave-private tile ----
    int tile = blockIdx.x * 8 + wv;            // 0..4687
    const float* w; const float* bias; float* ob; int V; int v0;
    if (tile < TGLOB) { w = wg;  bias = bg;  ob = out;                      V = VG; v0 = tile * 16; }
    else              { w = wsn; bias = bsv; ob = out + (size_t)BATCH * VG; V = VS; v0 = (tile - TGLOB) * 16; }

    int c  = l & 15;          // vocab col within tile AND h0 batch row
    int kg = l >> 4;          // k-quarter 0..3
    int vb = v0 + c;
    int vr = (vb < V) ? vb : (V - 1);
    const float4* __restrict__ wrow = (const float4*)(w + (size_t)vr * 512) + kg * 2;
    int swz = c & 7;
    const unsigned char* ha = &hlds[c * 1024];
    const unsigned char* hb = &hlds[(c + 16) * 1024];

    // ---- rolling 4-deep prefetch into registers ----
    float4 wb[4][2];
    #pragma unroll
    for (int p = 0; p < 4; p++) {
        wb[p][0] = wrow[p * 8];
        wb[p][1] = wrow[p * 8 + 1];
    }

    f32x4 acc0 = {0.f, 0.f, 0.f, 0.f};
    f32x4 acc1 = {0.f, 0.f, 0.f, 0.f};

    #pragma unroll
    for (int kc = 0; kc < 16; kc++) {
        float4 b0 = wb[kc & 3][0];
        float4 b1 = wb[kc & 3][1];
        if (kc + 4 < 16) {
            wb[kc & 3][0] = wrow[(kc + 4) * 8];
            wb[kc & 3][1] = wrow[(kc + 4) * 8 + 1];
        }
        int gr = ((kc * 4 + kg) ^ swz) << 4;
        s16x8 a0 = *(const s16x8*)(ha + gr);
        s16x8 a1 = *(const s16x8*)(hb + gr);
        s16x8 bf;
        bf[0] = f2bf(b0.x); bf[1] = f2bf(b0.y); bf[2] = f2bf(b0.z); bf[3] = f2bf(b0.w);
        bf[4] = f2bf(b1.x); bf[5] = f2bf(b1.y); bf[6] = f2bf(b1.z); bf[7] = f2bf(b1.w);
        acc0 = __builtin_amdgcn_mfma_f32_16x16x32_bf16(a0, bf, acc0, 0, 0, 0);
        acc1 = __builtin_amdgcn_mfma_f32_16x16x32_bf16(a1, bf, acc1, 0, 0, 0);
    }

    // ---- epilogue: C/D layout col=lane&15 (vocab), row=(lane>>4)*4+j (batch) ----
    if (vb < V) {
        float bia = bias[vb];
        #pragma unroll
        for (int j = 0; j < 4; j++) {
            int g0 = kg * 4 + j;
            ob[(size_t)g0 * V + vb]        = acc0[j] + bia;
            ob[(size_t)(g0 + 16) * V + vb] = acc1[j] + bia;
        }
    }
}

// ---------------------------------------------------------------------------
// K4: log-softmax pieces
// ---------------------------------------------------------------------------
__global__ __launch_bounds__(256) void k_lse_part(const float* __restrict__ out,
                                                  float* __restrict__ part) {
    int bx = blockIdx.x;
    int V, ci, pidx;
    const float* row;
    if (bx < 32 * PG) {
        int g = bx / PG; ci = bx % PG; V = VG;
        row = out + (size_t)g * VG;
        pidx = g * PG + ci;
    } else {
        int b2 = bx - 32 * PG;
        int g = b2 / PS; ci = b2 % PS; V = VS;
        row = out + (size_t)BATCH * VG + (size_t)g * VS;
        pidx = 32 * PG + g * PS + ci;
    }
    int t = threadIdx.x;
    float p = 0.f;
    int base = ci * 2048 + t * 8;
    #pragma unroll
    for (int jj = 0; jj < 8; jj++) {
        int idx = base + jj;
        if (idx < V) p += expf(row[idx]);
    }
    #pragma unroll
    for (int s = 1; s < 64; s <<= 1) p += __shfl_xor(p, s);
    __shared__ float wsum[4];
    if ((t & 63) == 0) wsum[t >> 6] = p;
    __syncthreads();
    if (t == 0) part[pidx] = wsum[0] + wsum[1] + wsum[2] + wsum[3];
}

__global__ __launch_bounds__(64) void k_lse_final(const float* __restrict__ part,
                                                  float* __restrict__ lse) {
    int t = threadIdx.x;
    int head = t >> 5, g = t & 31;
    float s = 0.f;
    if (head == 0) { for (int c = 0; c < PG; c++) s += part[g * PG + c]; }
    else           { for (int c = 0; c < PS; c++) s += part[32 * PG + g * PS + c]; }
    lse[t] = logf(s);
}

__global__ __launch_bounds__(256) void k_sub(float* __restrict__ out,
                                             const float* __restrict__ lse) {
    unsigned i4 = blockIdx.x * 256u + threadIdx.x;
    if (i4 >= 600000u) return;
    unsigned idx = i4 * 4u;
    float l;
    if (idx < 1600000u) l = lse[idx / 50000u];
    else                l = lse[32u + (idx - 1600000u) / 25000u];
    float4 v = *(float4*)(out + idx);
    v.x -= l; v.y -= l; v.z -= l; v.w -= l;
    *(float4*)(out + idx) = v;
}

// ---------------------------------------------------------------------------
extern "C" void kernel_launch(void* const* d_in, const int* in_sizes, int n_in,
                              void* d_out, int out_size, void* d_ws, size_t ws_size,
                              hipStream_t stream) {
    const float* x        = (const float*)d_in[0];
    const int*   ei       = (const int*)  d_in[1];
    const int*   et       = (const int*)  d_in[2];
    const float* basis    = (const float*)d_in[3];
    const float* comp     = (const float*)d_in[4];
    const float* root     = (const float*)d_in[5];
    const float* biasc    = (const float*)d_in[6];
    const float* wg       = (const float*)d_in[7];
    const float* bg       = (const float*)d_in[8];
    const float* wsn      = (const float*)d_in[9];
    const float* bsv      = (const float*)d_in[10];
    float* out = (float*)d_out;

    float* z     = out;
    float* part2 = out + (size_t)BATCH * ZI;
    unsigned* h0t  = (unsigned*)d_ws;            // 8192 uints = 32KB
    float*    plse = (float*)d_ws + 8192;
    float*    lse  = plse + 32 * PG + 32 * PS;

    k_conv     <<<BATCH, 512, 0, stream>>>(x, ei, et, comp, z);
    k_gemm_part<<<NCH * 4, 512, 0, stream>>>(z, root, basis, part2);
    k_h0       <<<BATCH, 256, 0, stream>>>(part2, biasc, h0t);
    k_logits7  <<<NBLK7, 512, 0, stream>>>(h0t, wg, bg, wsn, bsv, out);
    k_lse_part <<<32 * PG + 32 * PS, 256, 0, stream>>>(out, plse);
    k_lse_final<<<1, 64, 0, stream>>>(plse, lse);
    k_sub      <<<2344, 256, 0, stream>>>(out, lse);
}

// Round 9
// 78.236 us; speedup vs baseline: 1.0046x; 1.0046x over previous
//
#include <hip/hip_runtime.h>
#include <hip/hip_bf16.h>

#define BATCH 32
#define NNODE 2048
#define NEDGE 8192
#define DIM   512
#define NREL  8
#define VG    50000
#define VS    25000
#define ZI    4608           // 512 (root) + 8*512 (basis)
#define NCH   36             // 4608 / 128 i-chunks
#define NT_G  3125           // 50000/16 global-head wave-tiles
#define NT_S  1563           // ceil(25000/16) sense wave-tiles
#define TTOT  4688           // total wave-tiles
#define NBLK8 1172           // 1172 blocks x 4 waves = 4688 wave-tiles

typedef __attribute__((ext_vector_type(4))) float f32x4;
typedef __attribute__((ext_vector_type(8))) short s16x8;

// ---------------------------------------------------------------------------
// K1: per-batch edge scan (dst==0 only), builds z[g][0..4607]
// ---------------------------------------------------------------------------
__global__ __launch_bounds__(512) void k_conv(const float* __restrict__ x,
                                              const int* __restrict__ ei,
                                              const int* __restrict__ et,
                                              const float* __restrict__ comp,
                                              float* __restrict__ z) {
    int g = blockIdx.x;
    int t = threadIdx.x;
    int wv = t >> 6, lane = t & 63;
    __shared__ int elds[8 * 128];
    __shared__ int wcnt[8];
    const int* srcp = ei + (size_t)(g * 2 + 0) * NEDGE;
    const int* dstp = ei + (size_t)(g * 2 + 1) * NEDGE;

    int run = 0;
    for (int it = 0; it < 16; it++) {
        int e = wv * 1024 + it * 64 + lane;
        bool m = (dstp[e] == 0);
        unsigned long long mask = __ballot(m);
        int rank = __popcll(mask & ((1ull << lane) - 1ull));
        if (m && (run + rank) < 128) elds[wv * 128 + run + rank] = e;
        run += (int)__popcll(mask);
    }
    if (lane == 0) wcnt[wv] = (run > 128) ? 128 : run;
    __syncthreads();

    int d = t;
    float s0=0,s1=0,s2=0,s3=0,s4=0,s5=0,s6=0,s7=0;
    int   c0=0,c1=0,c2=0,c3=0,c4=0,c5=0,c6=0,c7=0;
    for (int w = 0; w < 8; w++) {
        int cw = wcnt[w];
        for (int i = 0; i < cw; i++) {
            int e = elds[w * 128 + i];
            int r = et[(size_t)g * NEDGE + e];
            int sn = srcp[e];
            float val = x[((size_t)g * NNODE + sn) * DIM + d];
            if (r == 0) { s0 += val; c0++; }
            if (r == 1) { s1 += val; c1++; }
            if (r == 2) { s2 += val; c2++; }
            if (r == 3) { s3 += val; c3++; }
            if (r == 4) { s4 += val; c4++; }
            if (r == 5) { s5 += val; c5++; }
            if (r == 6) { s6 += val; c6++; }
            if (r == 7) { s7 += val; c7++; }
        }
    }
    float sv[8] = {s0,s1,s2,s3,s4,s5,s6,s7};
    float inv[8];
    int   cv[8] = {c0,c1,c2,c3,c4,c5,c6,c7};
    #pragma unroll
    for (int r = 0; r < 8; r++) inv[r] = 1.0f / fmaxf((float)cv[r], 1.0f);

    z[(size_t)g * ZI + d] = x[((size_t)g * NNODE + 0) * DIM + d];
    #pragma unroll
    for (int b = 0; b < 8; b++) {
        float y = 0.f;
        #pragma unroll
        for (int r = 0; r < 8; r++) y += comp[r * 8 + b] * inv[r] * sv[r];
        z[(size_t)g * ZI + 512 + b * 512 + d] = y;
    }
}

// ---------------------------------------------------------------------------
// K2a: partial GEMM  part2[c][g][d] = sum_{i in chunk c} z[g][i] * M[i][d]
// ---------------------------------------------------------------------------
__global__ __launch_bounds__(512) void k_gemm_part(const float* __restrict__ z,
                                                   const float* __restrict__ root,
                                                   const float* __restrict__ basis,
                                                   float* __restrict__ part2) {
    int bx = blockIdx.x;
    int dt = bx & 3;
    int cc = bx >> 2;
    int t = threadIdx.x;
    int dl = t & 127, gq = t >> 7;
    __shared__ float ztT[128][33];
    #pragma unroll
    for (int rep = 0; rep < 8; rep++) {
        int flat = rep * 512 + t;
        int g = flat >> 7, i = flat & 127;
        ztT[i][g] = z[(size_t)g * ZI + cc * 128 + i];
    }
    __syncthreads();
    const float* M = (cc < 4) ? (root + (size_t)(cc * 128) * 512)
                              : (basis + (size_t)((cc - 4) * 128) * 512);
    float acc[8] = {0,0,0,0,0,0,0,0};
    for (int i = 0; i < 128; i++) {
        float m = M[(size_t)i * 512 + dt * 128 + dl];
        #pragma unroll
        for (int j = 0; j < 8; j++) acc[j] += ztT[i][gq * 8 + j] * m;
    }
    #pragma unroll
    for (int j = 0; j < 8; j++) {
        int g = gq * 8 + j;
        part2[((size_t)cc * 32 + g) * 512 + dt * 128 + dl] = acc[j];
    }
}

// ---------------------------------------------------------------------------
// K2b: h0 reduce + relu + pack bf16 pairs.  h0t[g*256 + p] = bf16(2p)|bf16(2p+1)<<16
// ---------------------------------------------------------------------------
__device__ __forceinline__ unsigned bf16rne(float f) {
    unsigned u = __float_as_uint(f);
    return (u + 0x7FFFu + ((u >> 16) & 1u)) >> 16;
}

__global__ __launch_bounds__(256) void k_h0(const float* __restrict__ part2,
                                            const float* __restrict__ bias_conv,
                                            unsigned* __restrict__ h0t) {
    int g = blockIdx.x;
    int p = threadIdx.x;          // pair index kp = 0..255
    int d0 = 2 * p;
    float v0 = bias_conv[d0], v1 = bias_conv[d0 + 1];
    for (int cc = 0; cc < NCH; cc++) {
        const float* pp = part2 + ((size_t)cc * 32 + g) * 512 + d0;
        v0 += pp[0];
        v1 += pp[1];
    }
    v0 = fmaxf(v0, 0.f);
    v1 = fmaxf(v1, 0.f);
    h0t[g * 256 + p] = bf16rne(v0) | (bf16rne(v1) << 16);
}

// ---------------------------------------------------------------------------
// K3 v8: wave-private streaming MFMA GEMV + fused log-softmax partials.
// 1172 blocks x 4 waves; each wave owns one 16-row x K=512 W tile (32KB),
// streamed via rolling 4-deep NONTEMPORAL register prefetch (W is single-use:
// NT bypasses L2 allocation -> less L2 churn, lower effective latency).
// h0 (A-fragments) in 32KB XOR-swizzled LDS, loaded once per block.
// Epilogue: logits store + per-tile exp-partials (16-lane butterfly) to
// part[tile*32+g] -> k_lse_part's 9.6MB re-read pass is eliminated.
// ---------------------------------------------------------------------------
__device__ __forceinline__ short f2bf(float f) {
    __hip_bfloat16 h = __float2bfloat16(f);
    return *reinterpret_cast<short*>(&h);
}

__global__ __launch_bounds__(256, 4) void k_logits8(const unsigned* __restrict__ h0t,
                                                    const float* __restrict__ wg,
                                                    const float* __restrict__ bg,
                                                    const float* __restrict__ wsn,
                                                    const float* __restrict__ bsv,
                                                    float* __restrict__ out,
                                                    float* __restrict__ part) {
    __shared__ __align__(16) unsigned char hlds[32768];   // h0 [32 g][1KB], 16B-XOR

    int t = threadIdx.x;          // 0..255
    int wv = t >> 6, l = t & 63;

    // ---- h0 -> LDS (16B-granule XOR by batch row); once per block ----
    #pragma unroll
    for (int rep = 0; rep < 8; rep++) {
        int idx = rep * 256 + t;               // uint4 index, 2048 total
        int g = idx >> 6, q = idx & 63;
        uint4 val = *(const uint4*)&h0t[idx * 4];
        *(uint4*)&hlds[g * 1024 + ((q ^ (g & 7)) << 4)] = val;
    }
    __syncthreads();

    // ---- wave-private tile ----
    int tile = blockIdx.x * 4 + wv;            // 0..4687
    const float* w; const float* bias; float* ob; int V; int v0;
    if (tile < NT_G) { w = wg;  bias = bg;  ob = out;                      V = VG; v0 = tile * 16; }
    else             { w = wsn; bias = bsv; ob = out + (size_t)BATCH * VG; V = VS; v0 = (tile - NT_G) * 16; }

    int c  = l & 15;          // vocab col within tile AND h0 batch row
    int kg = l >> 4;          // k-quarter 0..3
    int vb = v0 + c;
    int vr = (vb < V) ? vb : (V - 1);
    const f32x4* __restrict__ wrow = (const f32x4*)(w + (size_t)vr * 512) + kg * 2;
    int swz = c & 7;
    const unsigned char* ha = &hlds[c * 1024];
    const unsigned char* hb = &hlds[(c + 16) * 1024];

    // ---- rolling 4-deep nontemporal prefetch into registers ----
    f32x4 wb[4][2];
    #pragma unroll
    for (int p = 0; p < 4; p++) {
        wb[p][0] = __builtin_nontemporal_load(&wrow[p * 8]);
        wb[p][1] = __builtin_nontemporal_load(&wrow[p * 8 + 1]);
    }

    f32x4 acc0 = {0.f, 0.f, 0.f, 0.f};
    f32x4 acc1 = {0.f, 0.f, 0.f, 0.f};

    #pragma unroll
    for (int kc = 0; kc < 16; kc++) {
        f32x4 b0 = wb[kc & 3][0];
        f32x4 b1 = wb[kc & 3][1];
        if (kc + 4 < 16) {
            wb[kc & 3][0] = __builtin_nontemporal_load(&wrow[(kc + 4) * 8]);
            wb[kc & 3][1] = __builtin_nontemporal_load(&wrow[(kc + 4) * 8 + 1]);
        }
        int gr = ((kc * 4 + kg) ^ swz) << 4;
        s16x8 a0 = *(const s16x8*)(ha + gr);
        s16x8 a1 = *(const s16x8*)(hb + gr);
        s16x8 bf;
        bf[0] = f2bf(b0[0]); bf[1] = f2bf(b0[1]); bf[2] = f2bf(b0[2]); bf[3] = f2bf(b0[3]);
        bf[4] = f2bf(b1[0]); bf[5] = f2bf(b1[1]); bf[6] = f2bf(b1[2]); bf[7] = f2bf(b1[3]);
        acc0 = __builtin_amdgcn_mfma_f32_16x16x32_bf16(a0, bf, acc0, 0, 0, 0);
        acc1 = __builtin_amdgcn_mfma_f32_16x16x32_bf16(a1, bf, acc1, 0, 0, 0);
    }

    // ---- epilogue: C/D layout col=lane&15 (vocab), row=(lane>>4)*4+j (batch) ----
    float p0[4], p1[4];
    bool valid = (vb < V);
    float bia = valid ? bias[vb] : 0.f;
    #pragma unroll
    for (int j = 0; j < 4; j++) {
        float v0f = acc0[j] + bia;
        float v1f = acc1[j] + bia;
        int g0 = kg * 4 + j;
        if (valid) {
            ob[(size_t)g0 * V + vb]        = v0f;
            ob[(size_t)(g0 + 16) * V + vb] = v1f;
        }
        p0[j] = valid ? __expf(v0f) : 0.f;
        p1[j] = valid ? __expf(v1f) : 0.f;
    }
    // butterfly over the 16 lanes of this kg-group (bits 0..3 of lane id)
    #pragma unroll
    for (int s = 1; s < 16; s <<= 1) {
        #pragma unroll
        for (int j = 0; j < 4; j++) {
            p0[j] += __shfl_xor(p0[j], s);
            p1[j] += __shfl_xor(p1[j], s);
        }
    }
    if (c == 0) {
        float* pt = part + (size_t)tile * 32;
        #pragma unroll
        for (int j = 0; j < 4; j++) {
            pt[kg * 4 + j]      = p0[j];
            pt[kg * 4 + j + 16] = p1[j];
        }
    }
}

// ---------------------------------------------------------------------------
// K4a: lse[row] = log(sum over tiles of part[tile*32+g]); row = head*32+g
// ---------------------------------------------------------------------------
__global__ __launch_bounds__(256) void k_lse64(const float* __restrict__ part,
                                               float* __restrict__ lse) {
    int bx = blockIdx.x;           // 0..63
    int head = bx >> 5, g = bx & 31;
    int tbase = head ? NT_G : 0;
    int ntl   = head ? (TTOT - NT_G) : NT_G;
    int t = threadIdx.x;
    float s = 0.f;
    for (int i = t; i < ntl; i += 256)
        s += part[(size_t)(tbase + i) * 32 + g];
    #pragma unroll
    for (int m = 1; m < 64; m <<= 1) s += __shfl_xor(s, m);
    __shared__ float ws4[4];
    if ((t & 63) == 0) ws4[t >> 6] = s;
    __syncthreads();
    if (t == 0) lse[bx] = logf(ws4[0] + ws4[1] + ws4[2] + ws4[3]);
}

// ---------------------------------------------------------------------------
// K4b: out -= lse (broadcast per row)
// ---------------------------------------------------------------------------
__global__ __launch_bounds__(256) void k_sub(float* __restrict__ out,
                                             const float* __restrict__ lse) {
    unsigned i4 = blockIdx.x * 256u + threadIdx.x;
    if (i4 >= 600000u) return;
    unsigned idx = i4 * 4u;
    float l;
    if (idx < 1600000u) l = lse[idx / 50000u];
    else                l = lse[32u + (idx - 1600000u) / 25000u];
    float4 v = *(float4*)(out + idx);
    v.x -= l; v.y -= l; v.z -= l; v.w -= l;
    *(float4*)(out + idx) = v;
}

// ---------------------------------------------------------------------------
extern "C" void kernel_launch(void* const* d_in, const int* in_sizes, int n_in,
                              void* d_out, int out_size, void* d_ws, size_t ws_size,
                              hipStream_t stream) {
    const float* x        = (const float*)d_in[0];
    const int*   ei       = (const int*)  d_in[1];
    const int*   et       = (const int*)  d_in[2];
    const float* basis    = (const float*)d_in[3];
    const float* comp     = (const float*)d_in[4];
    const float* root     = (const float*)d_in[5];
    const float* biasc    = (const float*)d_in[6];
    const float* wg       = (const float*)d_in[7];
    const float* bg       = (const float*)d_in[8];
    const float* wsn      = (const float*)d_in[9];
    const float* bsv      = (const float*)d_in[10];
    float* out = (float*)d_out;

    float* z     = out;
    float* part2 = out + (size_t)BATCH * ZI;
    unsigned* h0t  = (unsigned*)d_ws;            // 8192 uints = 32KB
    float*    part = (float*)d_ws + 8192;        // 4688*32 floats = 600KB
    float*    lse  = part + (size_t)TTOT * 32;   // 64 floats

    k_conv     <<<BATCH, 512, 0, stream>>>(x, ei, et, comp, z);
    k_gemm_part<<<NCH * 4, 512, 0, stream>>>(z, root, basis, part2);
    k_h0       <<<BATCH, 256, 0, stream>>>(part2, biasc, h0t);
    k_logits8  <<<NBLK8, 256, 0, stream>>>(h0t, wg, bg, wsn, bsv, out, part);
    k_lse64    <<<64, 256, 0, stream>>>(part, lse);
    k_sub      <<<2344, 256, 0, stream>>>(out, lse);
}